// Round 10
// baseline (228.038 us; speedup 1.0000x reference)
//
#include <hip/hip_runtime.h>

#define B 8
#define C 64
#define H 128
#define W 128
#define HW (H * W)
#define OC 27
#define KK 9
#define COUT 64
#define KDIM 576           // 9*64
#define LDSROW 1152        // bytes per pixel row (576 * 2B)
#define NPIX 16            // pixels per k_main workgroup
#define NPAIR (NPIX * KK)  // 144

typedef __attribute__((ext_vector_type(8))) short s16x8;
typedef __attribute__((ext_vector_type(4))) float f32x4;

__device__ inline ushort f2bf(float f) {
    union { float f; unsigned u; } uv;
    uv.f = f;
    unsigned r = uv.u + 0x7FFF + ((uv.u >> 16) & 1);
    return (ushort)(r >> 16);
}
__device__ inline float bf2f(ushort u) {
    return __uint_as_float((unsigned)u << 16);
}

// ---------------------------------------------------------------------------
// Kernel 1: transpose x (NCHW fp32) -> xTb (NHWC bf16). XCD-chunked swizzle.
// ---------------------------------------------------------------------------
__global__ __launch_bounds__(256) void k_transpose_x(const float* __restrict__ x,
                                                     ushort* __restrict__ xTb) {
    __shared__ float lds[64][65];
    int j = blockIdx.x;
    int vb = (j & 7) * 256 + (j >> 3);
    int b = vb >> 8;
    int tile = vb & 255;
    int hw0 = tile * 64;
    int lane = threadIdx.x & 63;
    int cg = threadIdx.x >> 6;
#pragma unroll
    for (int r = 0; r < 16; ++r) {
        int c = cg * 16 + r;
        lds[c][lane] = x[(size_t)(b * C + c) * HW + hw0 + lane];
    }
    __syncthreads();
#pragma unroll
    for (int r = 0; r < 16; ++r) {
        int hwl = cg * 16 + r;
        xTb[(size_t)(b * HW + hw0 + hwl) * C + lane] = f2bf(lds[lane][hwl]);
    }
}

// ---------------------------------------------------------------------------
// Kernel 2: repack w -> wB[o][K] bf16, K = tap*64 + c.
// ---------------------------------------------------------------------------
__global__ __launch_bounds__(256) void k_prep_w(const float* __restrict__ w,
                                                ushort* __restrict__ wB) {
    int idx = blockIdx.x * 256 + threadIdx.x;
    if (idx >= COUT * KDIM) return;
    int o = idx / KDIM;
    int Kx = idx % KDIM;
    int k = Kx >> 6;
    int c = Kx & 63;
    wB[idx] = f2bf(w[(size_t)(o * C + c) * KK + k]);
}

// ---------------------------------------------------------------------------
// Kernel 2b: repack ow -> awB[32][576] bf16 (rows 27..31 = 0).
// ---------------------------------------------------------------------------
__global__ __launch_bounds__(256) void k_prep_aw(const float* __restrict__ ow,
                                                 ushort* __restrict__ awB) {
    int idx = blockIdx.x * 256 + threadIdx.x;
    if (idx >= 32 * KDIM) return;
    int o = idx / KDIM;
    int Kx = idx % KDIM;
    int tap = Kx >> 6;
    int c = Kx & 63;
    float v = (o < OC) ? ow[((size_t)o * C + c) * KK + tap] : 0.0f;
    awB[idx] = f2bf(v);
}

// ---------------------------------------------------------------------------
// Kernel 3: offset/mask conv (im2col MFMA GEMM) + fused meta production.
// ---------------------------------------------------------------------------
__global__ __launch_bounds__(256) void k_om(const ushort* __restrict__ xTb,
                                            const ushort* __restrict__ awB,
                                            const float* __restrict__ ob,
                                            float4* __restrict__ gW,
                                            int2* __restrict__ gO) {
    __shared__ __align__(16) char xwin[3 * 66 * 128];  // 25344 B
    int tid = threadIdx.x;
    int lane = tid & 63;
    int wv = tid >> 6;
    int j = blockIdx.x;
    int vb = (j & 7) * 256 + (j >> 3);
    int b = vb >> 8;
    int h = (vb >> 1) & 127;
    int w0 = (vb & 1) * 64;

    const ushort* xb = xTb + (size_t)b * (HW * C);
    int ch2 = tid & 31;
#pragma unroll
    for (int it = 0; it < 25; ++it) {
        int pi = it * 8 + (tid >> 5);
        if (pi < 198) {
            int row = pi / 66;
            int col = pi - row * 66;
            int y = h - 1 + row;
            int xc = w0 - 1 + col;
            unsigned v = 0;
            if ((unsigned)y < H && (unsigned)xc < W)
                v = *(const unsigned*)(xb + ((size_t)(y * W + xc) << 6) + ch2 * 2);
            int byte = (pi * 128 + ch2 * 4) ^ ((col & 7) << 4);
            *(unsigned*)(xwin + byte) = v;
        }
    }
    __syncthreads();

    f32x4 acc0 = {0.f, 0.f, 0.f, 0.f};
    f32x4 acc1 = {0.f, 0.f, 0.f, 0.f};
    int pixl = lane & 15;
    int q = lane >> 4;
    int base_col = wv * 16 + pixl;
    const ushort* a0 = awB + (size_t)pixl * KDIM + q * 8;
    const ushort* a1 = awB + (size_t)(16 + pixl) * KDIM + q * 8;
#pragma unroll
    for (int s = 0; s < 18; ++s) {
        int tap = s >> 1;
        int row = tap / 3;
        int cs = tap - row * 3;
        int col = base_col + cs;
        int c0b = ((s & 1) * 32 + q * 8) * 2;
        int byte = (((row * 66 + col) << 7) + c0b) ^ ((col & 7) << 4);
        s16x8 bfrag = *(const s16x8*)(xwin + byte);
        s16x8 af0 = *(const s16x8*)(a0 + s * 32);
        s16x8 af1 = *(const s16x8*)(a1 + s * 32);
        acc0 = __builtin_amdgcn_mfma_f32_16x16x32_bf16(af0, bfrag, acc0, 0, 0, 0);
        acc1 = __builtin_amdgcn_mfma_f32_16x16x32_bf16(af1, bfrag, acc1, 0, 0, 0);
    }

    __syncthreads();
    float* omt = (float*)xwin;
    {
        int pix = wv * 16 + pixl;
#pragma unroll
        for (int jj = 0; jj < 4; ++jj) {
            int oc = q * 4 + jj;
            omt[pix * 29 + oc] = acc0[jj] + ob[oc];
        }
#pragma unroll
        for (int jj = 0; jj < 4; ++jj) {
            int oc1 = 16 + q * 4 + jj;
            if (oc1 < OC) omt[pix * 29 + oc1] = acc1[jj] + ob[oc1];
        }
    }
    __syncthreads();

    size_t base9 = ((size_t)b * HW + h * W + w0) * KK;
    for (int t = tid; t < 64 * KK; t += 256) {
        int pix = t / 9;
        int k = t - pix * 9;
        float offx = omt[pix * 29 + k];
        float offy = omt[pix * 29 + 9 + k];
        float mlog = omt[pix * 29 + 18 + k];
        int dh = k / 3 - 1;
        int dw = k % 3 - 1;
        float mask = 1.0f / (1.0f + __expf(-mlog));
        float gx = (float)(w0 + pix + dw) + offx;
        float gy = (float)(h + dh) + offy;
        float x0f = floorf(gx), y0f = floorf(gy);
        int x0 = (int)x0f, y0 = (int)y0f;
        int x1 = x0 + 1, y1 = y0 + 1;
        float wx1 = gx - x0f, wy1 = gy - y0f;
        float wx0 = 1.0f - wx1, wy0 = 1.0f - wy1;
        float rw0 = ((unsigned)y0 < H) ? wy0 * mask : 0.0f;
        float rw1 = ((unsigned)y1 < H) ? wy1 * mask : 0.0f;
        int y0c = min(max(y0, 0), H - 1), y1c = min(max(y1, 0), H - 1);
        int colbase = min(max(x0, 0), W - 2);
        float cw0 = 0.0f, cw1 = 0.0f;
        if ((unsigned)x0 < W) { if (x0 == colbase) cw0 += wx0; else cw1 += wx0; }
        if ((unsigned)x1 < W) { if (x1 == colbase) cw0 += wx1; else cw1 += wx1; }
        gW[base9 + t] = make_float4(rw0 * cw0, rw0 * cw1, rw1 * cw0, rw1 * cw1);
        gO[base9 + t] = make_int2((y0c * W + colbase) * (C * 2),
                                  (y1c * W + colbase) * (C * 2));
    }
}

// ---------------------------------------------------------------------------
// Kernel 4 (template): M=0 real; M=1 no-MFMA; M=2 no-gather-loads; M=3 B-only.
// A1 is software-pipelined: issue pixel p+1's 36 dword loads (row base +
// lane*4 and ^128 for the other slot -> every lane holds both slots, no
// shuffle) before blending pixel p. Blend: 4 weight-selects + 8 FMA + pack.
// ---------------------------------------------------------------------------
template <int M>
__global__ __launch_bounds__(256, 4) void k_main(const ushort* __restrict__ xTb,
                                                 const float4* __restrict__ gW,
                                                 const int2* __restrict__ gO,
                                                 const ushort* __restrict__ wB,
                                                 const float* __restrict__ bias,
                                                 float* __restrict__ out,
                                                 float* __restrict__ scratch) {
    __shared__ __align__(16) char smem[NPIX * LDSROW];  // 18432 B
    __shared__ float4 mw_lds[NPAIR];
    __shared__ int2 mo_lds[NPAIR];

    int tid = threadIdx.x;
    int lane = tid & 63;
    int wv = tid >> 6;
    int jb = blockIdx.x;
    int vb = (jb & 7) * 1024 + (jb >> 3);
    int pb = vb * NPIX;
    int b = pb >> 14;
    int rem = pb & (HW - 1);
    int h = rem >> 7;
    int w0 = rem & (W - 1);

    if (M != 3) {
        size_t base9 = ((size_t)b * HW + rem) * KK;
        if (tid < NPAIR) mw_lds[tid] = gW[base9 + tid];
        if (tid < NPAIR) mo_lds[tid] = gO[base9 + tid];
    }
    __syncthreads();

    if (M != 3) {
        const char* xbase = (const char*)(xTb + (size_t)b * (HW * C));
        bool lo = lane < 32;
        int o1 = lane * 4, o2 = o1 ^ 128;
        int m31 = lane & 31;
        int p0 = wv * 4;

        unsigned rA0[KK], rA1[KK], rA2[KK], rA3[KK];
        unsigned rB0[KK], rB1[KK], rB2[KK], rB3[KK];

#define ISSUE(P, R0, R1, R2, R3)                                             \
    {                                                                        \
        _Pragma("unroll") for (int k = 0; k < KK; ++k) {                     \
            int2 mo = mo_lds[(P)*9 + k];                                     \
            if (M == 2) {                                                    \
                R0[k] = (unsigned)mo.x * 2654435761u + lane;                 \
                R1[k] = (unsigned)mo.x + 77u * lane;                         \
                R2[k] = (unsigned)mo.y * 2654435761u + lane;                 \
                R3[k] = (unsigned)mo.y + 77u * lane;                         \
            } else {                                                         \
                const char* b0 = xbase + mo.x;                               \
                const char* b1 = xbase + mo.y;                               \
                R0[k] = *(const unsigned*)(b0 + o1);                         \
                R1[k] = *(const unsigned*)(b0 + o2);                         \
                R2[k] = *(const unsigned*)(b1 + o1);                         \
                R3[k] = *(const unsigned*)(b1 + o2);                         \
            }                                                                \
        }                                                                    \
    }                                                                        \
    __builtin_amdgcn_sched_barrier(0);

#define BLEND(P, R0, R1, R2, R3)                                             \
    {                                                                        \
        int vlds = (P)*LDSROW + ((m31 * 4) ^ (((P)&7) << 4));                \
        _Pragma("unroll") for (int k = 0; k < KK; ++k) {                     \
            float4 mw = mw_lds[(P)*9 + k];                                   \
            float wA = lo ? mw.x : mw.y;                                     \
            float wB_ = lo ? mw.y : mw.x;                                    \
            float wC = lo ? mw.z : mw.w;                                     \
            float wD = lo ? mw.w : mw.z;                                     \
            float e = __uint_as_float(R0[k] << 16) * wA +                    \
                      __uint_as_float(R1[k] << 16) * wB_ +                   \
                      __uint_as_float(R2[k] << 16) * wC +                    \
                      __uint_as_float(R3[k] << 16) * wD;                     \
            float o = __uint_as_float(R0[k] & 0xFFFF0000u) * wA +            \
                      __uint_as_float(R1[k] & 0xFFFF0000u) * wB_ +           \
                      __uint_as_float(R2[k] & 0xFFFF0000u) * wC +            \
                      __uint_as_float(R3[k] & 0xFFFF0000u) * wD;             \
            unsigned pk;                                                     \
            asm("v_cvt_pk_bf16_f32 %0, %1, %2" : "=v"(pk) : "v"(e), "v"(o)); \
            if (lane < 32) *(unsigned*)(smem + vlds + k * 128) = pk;         \
        }                                                                    \
    }

        ISSUE(p0 + 0, rA0, rA1, rA2, rA3)
        ISSUE(p0 + 1, rB0, rB1, rB2, rB3)
        BLEND(p0 + 0, rA0, rA1, rA2, rA3)
        ISSUE(p0 + 2, rA0, rA1, rA2, rA3)
        BLEND(p0 + 1, rB0, rB1, rB2, rB3)
        ISSUE(p0 + 3, rB0, rB1, rB2, rB3)
        BLEND(p0 + 2, rA0, rA1, rA2, rA3)
        BLEND(p0 + 3, rB0, rB1, rB2, rB3)
#undef ISSUE
#undef BLEND
    }
    __syncthreads();

    if (M == 1) {  // keep A1 live without MFMA
        float s = *(float*)(smem + tid * 64) + *(float*)(smem + tid * 64 + 32);
        scratch[((size_t)jb * 256 + tid) & 0x3FFFF] = s;
        return;
    }

    f32x4 acc;
#pragma unroll
    for (int j = 0; j < 4; ++j) acc[j] = bias[wv * 16 + (lane >> 4) * 4 + j];

    int pix = lane & 15;
    const ushort* wrow = wB + (size_t)(wv * 16 + pix) * KDIM + (lane >> 4) * 8;
#pragma unroll
    for (int s = 0; s < 18; ++s) {
        int kbyte = s * 64 + (lane >> 4) * 16;
        int byte = (pix * LDSROW + kbyte) ^ ((pix & 7) << 4);
        s16x8 bfrag = *(const s16x8*)(smem + byte);
        s16x8 afrag = *(const s16x8*)(wrow + s * 32);
        acc = __builtin_amdgcn_mfma_f32_16x16x32_bf16(afrag, bfrag, acc, 0, 0, 0);
    }

    if (M == 0) {
        float* obase =
            out + ((size_t)(b * COUT + wv * 16 + (lane >> 4) * 4) * HW) + h * W + w0;
#pragma unroll
        for (int j = 0; j < 4; ++j) obase[(size_t)j * HW + pix] = acc[j];
    } else {
#pragma unroll
        for (int j = 0; j < 4; ++j)
            scratch[(((size_t)jb * 256 + tid) * 4 + j) & 0x3FFFF] = acc[j];
    }
}

// ---------------------------------------------------------------------------
extern "C" void kernel_launch(void* const* d_in, const int* in_sizes, int n_in,
                              void* d_out, int out_size, void* d_ws, size_t ws_size,
                              hipStream_t stream) {
    const float* x = (const float*)d_in[0];
    const float* ow = (const float*)d_in[1];
    const float* ob = (const float*)d_in[2];
    const float* w = (const float*)d_in[3];
    const float* bias = (const float*)d_in[4];
    float* out = (float*)d_out;

    float4* gW = (float4*)d_ws;                         // 18.9 MB
    int2* gO = (int2*)(gW + (size_t)B * HW * KK);       //  9.4 MB
    ushort* xTb = (ushort*)(gO + (size_t)B * HW * KK);  // 16.8 MB
    ushort* wB = xTb + (size_t)B * HW * C;
    ushort* awB = wB + (size_t)COUT * KDIM;
    float* scratch = (float*)(awB + (size_t)32 * KDIM);  // 1 MB ablation scratch
    // total ~46.2 MB

    hipLaunchKernelGGL(k_transpose_x, dim3(B * 256), dim3(256), 0, stream, x, xTb);
    hipLaunchKernelGGL(k_prep_w, dim3((COUT * KDIM + 255) / 256), dim3(256), 0,
                       stream, w, wB);
    hipLaunchKernelGGL(k_prep_aw, dim3((32 * KDIM + 255) / 256), dim3(256), 0,
                       stream, ow, awB);
    hipLaunchKernelGGL(k_om, dim3(B * H * 2), dim3(256), 0, stream, xTb, awB, ob, gW, gO);
    hipLaunchKernelGGL(HIP_KERNEL_NAME(k_main<0>), dim3(B * HW / NPIX), dim3(256), 0,
                       stream, xTb, gW, gO, wB, bias, out, scratch);
    // ---- ablation dispatches (1/8 grid, scratch only) ----
    hipLaunchKernelGGL(HIP_KERNEL_NAME(k_main<4>), dim3(1024), dim3(256), 0,
                       stream, xTb, gW, gO, wB, bias, out, scratch);  // full ref
    hipLaunchKernelGGL(HIP_KERNEL_NAME(k_main<1>), dim3(1024), dim3(256), 0,
                       stream, xTb, gW, gO, wB, bias, out, scratch);  // no MFMA
    hipLaunchKernelGGL(HIP_KERNEL_NAME(k_main<2>), dim3(1024), dim3(256), 0,
                       stream, xTb, gW, gO, wB, bias, out, scratch);  // no gathers
    hipLaunchKernelGGL(HIP_KERNEL_NAME(k_main<3>), dim3(1024), dim3(256), 0,
                       stream, xTb, gW, gO, wB, bias, out, scratch);  // B only
}